// Round 1
// baseline (141.345 us; speedup 1.0000x reference)
//
#include <hip/hip_runtime.h>
#include <hip/hip_bf16.h>

#define DEV __device__ __forceinline__

typedef __attribute__((ext_vector_type(8)))  __bf16 bf16x8;
typedef __attribute__((ext_vector_type(4)))  int    int4v;
typedef __attribute__((ext_vector_type(16))) float  vfloat16;

// pack two fp32 -> one dword of two bf16 (RNE), low half = first arg
DEV int pkbf(float a, float b) {
    __hip_bfloat162 h = __float22bfloat162_rn(make_float2(a, b));
    int r;
    __builtin_memcpy(&r, &h, sizeof(r));
    return r;
}

DEV bf16x8 i4_to_frag(int4v v) { return __builtin_bit_cast(bf16x8, v); }

DEV int xor32i(int v) { return __shfl_xor(v, 32, 64); }

DEV vfloat16 mfma32(bf16x8 a, bf16x8 b, vfloat16 c) {
    return __builtin_amdgcn_mfma_f32_32x32x16_bf16(a, b, c, 0, 0, 0);
}

// ---- C-layout (8 regs = rows r0..r15 of a 16-row group) -> B-frag (K=16) ----
// C layout: col=lane&31, row=(reg&3)+8*(reg>>2)+4*h   (h = lane>=32)
// B layout: n=lane&31,  k=(lane>>5)*8+j  (j = vector elem)
DEV bf16x8 tlo8(float r0, float r1, float r2, float r3,
                float r4, float r5, float r6, float r7, bool h) {
    int R0 = pkbf(r0, r1);   // rows (0,1)+4h of group
    int R1 = pkbf(r2, r3);   // rows (2,3)+4h
    int R2 = pkbf(r4, r5);   // rows (8,9)+4h
    int R3 = pkbf(r6, r7);   // rows (10,11)+4h
    // value the OTHER half-wave needs:
    int S0 = h ? R0 : R2;
    int S1 = h ? R1 : R3;
    int Y0 = xor32i(S0);
    int Y1 = xor32i(S1);
    int4v v;
    v.x = h ? Y0 : R0;   // k slots j=0,1
    v.y = h ? Y1 : R1;   // j=2,3
    v.z = h ? R2 : Y0;   // j=4,5
    v.w = h ? R3 : Y1;   // j=6,7
    return i4_to_frag(v);
}

// A-frag: A[m][k_global], m=lane&31, k_global = koff + 8*h + j.
// W is row-major (K, ld): W[k][m] = W[k*ld + m]. Rows m>=Mact are zero.
// If bias != null, k_global == K slot carries bias[m] (k-slot bias trick).
DEV bf16x8 make_afrag(const float* __restrict__ W, const float* __restrict__ bias,
                      int ld, int Mact, int K, int koff, int lane) {
    int m = lane & 31;
    int h = lane >> 5;
    int d[4];
#pragma unroll
    for (int i = 0; i < 4; ++i) {
        int k0 = koff + h * 8 + 2 * i;
        int k1 = k0 + 1;
        float w0 = 0.f, w1 = 0.f;
        if (m < Mact) {
            if (k0 < K) w0 = W[k0 * ld + m];
            else if (bias && k0 == K) w0 = bias[m];
            if (k1 < K) w1 = W[k1 * ld + m];
            else if (bias && k1 == K) w1 = bias[m];
        }
        d[i] = pkbf(w0, w1);
    }
    int4v v; v.x = d[0]; v.y = d[1]; v.z = d[2]; v.w = d[3];
    return i4_to_frag(v);
}

// bias vector in C layout (all 32 rows)
DEV vfloat16 bvec32(const float* __restrict__ b, int lane) {
    int h = lane >> 5;
    vfloat16 v;
#pragma unroll
    for (int reg = 0; reg < 16; ++reg)
        v[reg] = b[(reg & 3) + 8 * (reg >> 2) + 4 * h];
    return v;
}
// bias vector, only rows 0..15 populated (regs 0..7), rest 0
DEV vfloat16 bvec16(const float* __restrict__ b, int lane) {
    int h = lane >> 5;
    vfloat16 v;
#pragma unroll
    for (int reg = 0; reg < 16; ++reg)
        v[reg] = (reg < 8) ? b[(reg & 3) + 8 * (reg >> 2) + 4 * h] : 0.f;
    return v;
}

// B-frag for layer1: x (4 feats) in k=0..3, 1.0 in k=4 (bias slot); h=1 lanes zero
DEV bf16x8 make_b1(float4 xa, bool act) {
    int4v v;
    v.x = act ? pkbf(xa.x, xa.y) : 0;
    v.y = act ? pkbf(xa.z, xa.w) : 0;
    v.z = act ? 0x00003f80 : 0;   // bf16(1.0) at k=4, 0 at k=5
    v.w = 0;
    return i4_to_frag(v);
}

struct Frags {
    bf16x8 A1, A2lo, A2hi, A3lo, A3hi;
    vfloat16 b2, b3;
};

DEV vfloat16 zero16() {
    vfloat16 z;
#pragma unroll
    for (int i = 0; i < 16; ++i) z[i] = 0.f;
    return z;
}

// 3-layer MLP: D=4 -> 32 -> 32 -> 16, relu after L1/L2, returns pre-relu C3 (regs 0..7 valid)
DEV vfloat16 run_mlp3(bf16x8 B1, const Frags& F, bool h) {
    vfloat16 C = mfma32(F.A1, B1, zero16());
#pragma unroll
    for (int i = 0; i < 16; ++i) C[i] = fmaxf(C[i], 0.f);
    bf16x8 Blo = tlo8(C[0], C[1], C[2], C[3], C[4], C[5], C[6], C[7], h);
    bf16x8 Bhi = tlo8(C[8], C[9], C[10], C[11], C[12], C[13], C[14], C[15], h);
    vfloat16 C2 = mfma32(F.A2lo, Blo, F.b2);
    C2 = mfma32(F.A2hi, Bhi, C2);
#pragma unroll
    for (int i = 0; i < 16; ++i) C2[i] = fmaxf(C2[i], 0.f);
    Blo = tlo8(C2[0], C2[1], C2[2], C2[3], C2[4], C2[5], C2[6], C2[7], h);
    Bhi = tlo8(C2[8], C2[9], C2[10], C2[11], C2[12], C2[13], C2[14], C2[15], h);
    vfloat16 C3 = mfma32(F.A3lo, Blo, F.b3);
    C3 = mfma32(F.A3hi, Bhi, C3);
    return C3;
}

__global__ __launch_bounds__(256, 4)
void dqn_kernel(const float* __restrict__ x, const int* __restrict__ selp,
                const float* __restrict__ oW1, const float* __restrict__ ob1,
                const float* __restrict__ oW2, const float* __restrict__ ob2,
                const float* __restrict__ oW3, const float* __restrict__ ob3,
                const float* __restrict__ sW1, const float* __restrict__ sb1,
                const float* __restrict__ sW2, const float* __restrict__ sb2,
                const float* __restrict__ sW3, const float* __restrict__ sb3,
                const float* __restrict__ gW1, const float* __restrict__ gb1,
                const float* __restrict__ gW2, const float* __restrict__ gb2,
                float* __restrict__ out)
{
    __shared__ float lds[2][8][64];

    const int tid  = threadIdx.x;
    const int lane = tid & 63;
    const int wave = tid >> 6;
    const int pair = wave >> 1;
    const bool oddw = (wave & 1) != 0;
    const bool h = lane >= 32;
    const int c = lane & 31;
    const int sel = *selp;
    const int base = (blockIdx.x * 2 + pair) * 32;   // 32 batch rows per wave-pair

    // "other"-MLP weight fragments (b1 rides the k=4 slot of A1)
    Frags Fo;
    Fo.A1   = make_afrag(oW1, ob1,     32, 32, 4, 0, lane);
    Fo.A2lo = make_afrag(oW2, nullptr, 32, 32, 32, 0, lane);
    Fo.A2hi = make_afrag(oW2, nullptr, 32, 32, 32, 16, lane);
    Fo.A3lo = make_afrag(oW3, nullptr, 16, 16, 32, 0, lane);
    Fo.A3hi = make_afrag(oW3, nullptr, 16, 16, 32, 16, lane);
    Fo.b2 = bvec32(ob2, lane);
    Fo.b3 = bvec16(ob3, lane);

    const float* xrow = x + (size_t)(base + c) * 128;   // meaningful for lanes 0..31

    float sum[8] = {0.f, 0.f, 0.f, 0.f, 0.f, 0.f, 0.f, 0.f};
    const int a0 = oddw ? 16 : 0;

    float4 xa = make_float4(0.f, 0.f, 0.f, 0.f);
    if (!h) xa = *(const float4*)(xrow + 4 * a0);
#pragma unroll
    for (int a = a0; a < a0 + 16; ++a) {
        float4 xn = make_float4(0.f, 0.f, 0.f, 0.f);
        if (!h && (a + 1 < a0 + 16)) xn = *(const float4*)(xrow + 4 * (a + 1));  // prefetch
        bf16x8 B1 = make_b1(xa, !h);
        vfloat16 C3 = run_mlp3(B1, Fo, h);
        if (a != sel) {
#pragma unroll
            for (int i = 0; i < 8; ++i) sum[i] += fmaxf(C3[i], 0.f);
        }
        xa = xn;
    }

    // combine partial agent-sums across the wave pair
    if (oddw) {
#pragma unroll
        for (int i = 0; i < 8; ++i) lds[pair][i][lane] = sum[i];
    }
    __syncthreads();
    if (!oddw) {
#pragma unroll
        for (int i = 0; i < 8; ++i) sum[i] += lds[pair][i][lane];

        // selected-agent MLP
        Frags Fs;
        Fs.A1   = make_afrag(sW1, sb1,     32, 32, 4, 0, lane);
        Fs.A2lo = make_afrag(sW2, nullptr, 32, 32, 32, 0, lane);
        Fs.A2hi = make_afrag(sW2, nullptr, 32, 32, 32, 16, lane);
        Fs.A3lo = make_afrag(sW3, nullptr, 16, 16, 32, 0, lane);
        Fs.A3hi = make_afrag(sW3, nullptr, 16, 16, 32, 16, lane);
        Fs.b2 = bvec32(sb2, lane);
        Fs.b3 = bvec16(sb3, lane);

        float4 xs = make_float4(0.f, 0.f, 0.f, 0.f);
        if (!h) xs = *(const float4*)(xrow + 4 * sel);
        bf16x8 B1s = make_b1(xs, !h);
        vfloat16 C3s = run_mlp3(B1s, Fs, h);
        float selo[8];
#pragma unroll
        for (int i = 0; i < 8; ++i) selo[i] = fmaxf(C3s[i], 0.f);

        // gate layer 1: concat([sel_out, sum_other]) @ gW1 + gb1, relu
        bf16x8 Ag_lo = make_afrag(gW1, nullptr, 32, 32, 32, 0, lane);
        bf16x8 Ag_hi = make_afrag(gW1, nullptr, 32, 32, 32, 16, lane);
        vfloat16 gb1v = bvec32(gb1, lane);
        bf16x8 Bg_lo = tlo8(selo[0], selo[1], selo[2], selo[3],
                            selo[4], selo[5], selo[6], selo[7], h);
        bf16x8 Bg_hi = tlo8(sum[0], sum[1], sum[2], sum[3],
                            sum[4], sum[5], sum[6], sum[7], h);
        vfloat16 G = mfma32(Ag_lo, Bg_lo, gb1v);
        G = mfma32(Ag_hi, Bg_hi, G);
#pragma unroll
        for (int i = 0; i < 16; ++i) G[i] = fmaxf(G[i], 0.f);

        // gate layer 2 (32 -> 2) in fp32 VALU + cross-half reduce
        float q0 = 0.f, q1 = 0.f;
#pragma unroll
        for (int reg = 0; reg < 16; ++reg) {
            int row = (reg & 3) + 8 * (reg >> 2) + (h ? 4 : 0);
            q0 += G[reg] * gW2[row * 2 + 0];
            q1 += G[reg] * gW2[row * 2 + 1];
        }
        q0 += __shfl_xor(q0, 32, 64);
        q1 += __shfl_xor(q1, 32, 64);
        q0 += gb2[0];
        q1 += gb2[1];

        if (!h) {
            int act = (int)xs.w;           // x in [0,1) -> 0; clamp like take_along_axis
            act = act < 0 ? 0 : (act > 1 ? 1 : act);
            out[base + c] = act ? q1 : q0;
        }
    }
}

extern "C" void kernel_launch(void* const* d_in, const int* in_sizes, int n_in,
                              void* d_out, int out_size, void* d_ws, size_t ws_size,
                              hipStream_t stream) {
    const float* x   = (const float*)d_in[0];
    const int*   sel = (const int*)d_in[1];
    const float* oW1 = (const float*)d_in[2];
    const float* ob1 = (const float*)d_in[3];
    const float* oW2 = (const float*)d_in[4];
    const float* ob2 = (const float*)d_in[5];
    const float* oW3 = (const float*)d_in[6];
    const float* ob3 = (const float*)d_in[7];
    const float* sW1 = (const float*)d_in[8];
    const float* sb1 = (const float*)d_in[9];
    const float* sW2 = (const float*)d_in[10];
    const float* sb2 = (const float*)d_in[11];
    const float* sW3 = (const float*)d_in[12];
    const float* sb3 = (const float*)d_in[13];
    const float* gW1 = (const float*)d_in[14];
    const float* gb1 = (const float*)d_in[15];
    const float* gW2 = (const float*)d_in[16];
    const float* gb2 = (const float*)d_in[17];
    float* out = (float*)d_out;

    const int B = in_sizes[0] / 128;       // 65536
    const int blocks = B / 64;             // 64 batch rows per block (2 wave-pairs)
    dqn_kernel<<<blocks, 256, 0, stream>>>(x, sel,
                                           oW1, ob1, oW2, ob2, oW3, ob3,
                                           sW1, sb1, sW2, sb2, sW3, sb3,
                                           gW1, gb1, gW2, gb2, out);
}

// Round 2
// 134.182 us; speedup vs baseline: 1.0534x; 1.0534x over previous
//
#include <hip/hip_runtime.h>
#include <hip/hip_bf16.h>

#define DEV __device__ __forceinline__

typedef __attribute__((ext_vector_type(8)))  __bf16    bf16x8;
typedef __attribute__((ext_vector_type(4)))  int       int4v;
typedef __attribute__((ext_vector_type(2)))  unsigned  uint2v;
typedef __attribute__((ext_vector_type(16))) float     vfloat16;

#if __has_builtin(__builtin_amdgcn_permlane32_swap)
#define HAVE_PLSWAP 1
#endif

// pack two fp32 -> one dword of two bf16 (RNE), low half = first arg
DEV int pkbf(float a, float b) {
    __hip_bfloat162 h = __float22bfloat162_rn(make_float2(a, b));
    int r;
    __builtin_memcpy(&r, &h, sizeof(r));
    return r;
}

DEV bf16x8 i4_to_frag(int4v v) { return __builtin_bit_cast(bf16x8, v); }

DEV vfloat16 mfma32(bf16x8 a, bf16x8 b, vfloat16 c) {
    return __builtin_amdgcn_mfma_f32_32x32x16_bf16(a, b, c, 0, 0, 0);
}

// ---- C-layout 8-reg group (rows 0..15 of a 16-row band) -> B-frag (K=16) ----
// C layout: col=lane&31, row=(reg&3)+8*(reg>>2)+4*h   (h = lane>=32)
// B layout: n=lane&31,  k=(lane>>5)*8+j  (j = bf16 elem idx)
// Applies ReLU while packing.  Pure-VALU via v_permlane32_swap_b32 (gfx950).
DEV bf16x8 xposeB(float c0, float c1, float c2, float c3,
                  float c4, float c5, float c6, float c7, bool h) {
    int R0 = pkbf(fmaxf(c0, 0.f), fmaxf(c1, 0.f));   // rows (0,1)+4h
    int R1 = pkbf(fmaxf(c2, 0.f), fmaxf(c3, 0.f));   // rows (2,3)+4h
    int R2 = pkbf(fmaxf(c4, 0.f), fmaxf(c5, 0.f));   // rows (8,9)+4h
    int R3 = pkbf(fmaxf(c6, 0.f), fmaxf(c7, 0.f));   // rows (10,11)+4h
#ifdef HAVE_PLSWAP
    // swap(R0,R2): .x = [R0_lo|R2_lo] (=rows0,1 / 8,9 -> B.x)
    //              .y = [R0_hi|R2_hi] (=rows4,5 / 12,13 -> B.z)
    uint2v p0 = __builtin_amdgcn_permlane32_swap((unsigned)R0, (unsigned)R2, false, false);
    uint2v p1 = __builtin_amdgcn_permlane32_swap((unsigned)R1, (unsigned)R3, false, false);
    int4v v;
    v.x = (int)p0.x; v.y = (int)p1.x; v.z = (int)p0.y; v.w = (int)p1.y;
#else
    int S0 = h ? R0 : R2;
    int S1 = h ? R1 : R3;
    int Y0 = __shfl_xor(S0, 32, 64);
    int Y1 = __shfl_xor(S1, 32, 64);
    int4v v;
    v.x = h ? Y0 : R0;
    v.y = h ? Y1 : R1;
    v.z = h ? R2 : Y0;
    v.w = h ? R3 : Y1;
#endif
    return i4_to_frag(v);
}

// A-frag: A[m][k_global], m=lane&31, k_global = koff + 8*h + j.
// W row-major (K, ld): W[k][m].  Rows m>=Mact zero; k>=K zero.
DEV bf16x8 make_afrag(const float* __restrict__ W, int ld, int Mact, int K,
                      int koff, int lane) {
    int m = lane & 31;
    int h = lane >> 5;
    int d[4];
#pragma unroll
    for (int i = 0; i < 4; ++i) {
        int k0 = koff + h * 8 + 2 * i;
        int k1 = k0 + 1;
        float w0 = 0.f, w1 = 0.f;
        if (m < Mact) {
            if (k0 < K) w0 = W[k0 * ld + m];
            if (k1 < K) w1 = W[k1 * ld + m];
        }
        d[i] = pkbf(w0, w1);
    }
    int4v v; v.x = d[0]; v.y = d[1]; v.z = d[2]; v.w = d[3];
    return i4_to_frag(v);
}

// bias vector in C layout (all 32 rows)
DEV vfloat16 bvec32(const float* __restrict__ b, int lane) {
    int h = lane >> 5;
    vfloat16 v;
#pragma unroll
    for (int reg = 0; reg < 16; ++reg)
        v[reg] = b[(reg & 3) + 8 * (reg >> 2) + 4 * h];
    return v;
}
// bias vector, only rows 0..15 populated (regs 0..7), upper 8 zero
DEV vfloat16 bvec16(const float* __restrict__ b, int lane) {
    int h = lane >> 5;
    vfloat16 v;
#pragma unroll
    for (int reg = 0; reg < 16; ++reg)
        v[reg] = (reg < 8) ? b[(reg & 3) + 8 * (reg >> 2) + 4 * h] : 0.f;
    return v;
}

// B-frag for layer1: x (4 feats) in k=0..3; h-lanes (k=8..15) hold zeros
// because xa is never loaded there (stays 0).
DEV bf16x8 make_b1(float4 xa) {
    int4v v;
    v.x = pkbf(xa.x, xa.y);
    v.y = pkbf(xa.z, xa.w);
    v.z = 0;
    v.w = 0;
    return i4_to_frag(v);
}

struct Frags {
    bf16x8 A1, A2lo, A2hi, A3lo, A3hi;
    vfloat16 c1, b2, b3;   // biases pre-arranged as MFMA C-operand inits
};

DEV void load_frags(Frags& F,
                    const float* __restrict__ W1, const float* __restrict__ b1,
                    const float* __restrict__ W2, const float* __restrict__ b2,
                    const float* __restrict__ W3, const float* __restrict__ b3,
                    int lane) {
    F.A1   = make_afrag(W1, 32, 32, 4, 0, lane);
    F.A2lo = make_afrag(W2, 32, 32, 32, 0, lane);
    F.A2hi = make_afrag(W2, 32, 32, 32, 16, lane);
    F.A3lo = make_afrag(W3, 16, 16, 32, 0, lane);
    F.A3hi = make_afrag(W3, 16, 16, 32, 16, lane);
    F.c1 = bvec32(b1, lane);
    F.b2 = bvec32(b2, lane);
    F.b3 = bvec16(b3, lane);
}

// 3-layer MLP: 4 -> 32 -> 32 -> 16, relu after L1/L2; returns pre-relu C3
// (regs 0..7 valid, 8..15 garbage-but-unused)
DEV vfloat16 run_mlp3(bf16x8 B1, const Frags& F, bool h) {
    vfloat16 C = mfma32(F.A1, B1, F.c1);
    bf16x8 Blo = xposeB(C[0], C[1], C[2], C[3], C[4], C[5], C[6], C[7], h);
    bf16x8 Bhi = xposeB(C[8], C[9], C[10], C[11], C[12], C[13], C[14], C[15], h);
    vfloat16 C2 = mfma32(F.A2lo, Blo, F.b2);
    C2 = mfma32(F.A2hi, Bhi, C2);
    Blo = xposeB(C2[0], C2[1], C2[2], C2[3], C2[4], C2[5], C2[6], C2[7], h);
    Bhi = xposeB(C2[8], C2[9], C2[10], C2[11], C2[12], C2[13], C2[14], C2[15], h);
    vfloat16 C3 = mfma32(F.A3lo, Blo, F.b3);
    C3 = mfma32(F.A3hi, Bhi, C3);
    return C3;
}

__global__ __launch_bounds__(256, 3)
void dqn_kernel(const float* __restrict__ x, const int* __restrict__ selp,
                const float* __restrict__ oW1, const float* __restrict__ ob1,
                const float* __restrict__ oW2, const float* __restrict__ ob2,
                const float* __restrict__ oW3, const float* __restrict__ ob3,
                const float* __restrict__ sW1, const float* __restrict__ sb1,
                const float* __restrict__ sW2, const float* __restrict__ sb2,
                const float* __restrict__ sW3, const float* __restrict__ sb3,
                const float* __restrict__ gW1, const float* __restrict__ gb1,
                const float* __restrict__ gW2, const float* __restrict__ gb2,
                float* __restrict__ out)
{
    __shared__ float lds[2][8][64];

    const int tid  = threadIdx.x;
    const int lane = tid & 63;
    const int wave = tid >> 6;
    const int pair = wave >> 1;
    const bool oddw = (wave & 1) != 0;
    const bool h = lane >= 32;
    const int c = lane & 31;
    const int sel = *selp;
    const int base = (blockIdx.x * 2 + pair) * 32;   // 32 batch rows per wave-pair

    Frags Fo;
    load_frags(Fo, oW1, ob1, oW2, ob2, oW3, ob3, lane);

    const float* xrow = x + (size_t)(base + c) * 128;   // meaningful for lanes 0..31

    float sum[8] = {0.f, 0.f, 0.f, 0.f, 0.f, 0.f, 0.f, 0.f};
    const int a0 = oddw ? 16 : 0;

    float4 xa = make_float4(0.f, 0.f, 0.f, 0.f);
    if (!h) xa = *(const float4*)(xrow + 4 * a0);
#pragma unroll 2
    for (int a = a0; a < a0 + 16; ++a) {
        float4 xn = make_float4(0.f, 0.f, 0.f, 0.f);
        if (!h && (a + 1 < a0 + 16)) xn = *(const float4*)(xrow + 4 * (a + 1));  // prefetch
        bf16x8 B1 = make_b1(xa);
        vfloat16 C3 = run_mlp3(B1, Fo, h);
        if (a != sel) {
#pragma unroll
            for (int i = 0; i < 8; ++i) sum[i] += fmaxf(C3[i], 0.f);
        }
        xa = xn;
    }

    // combine partial agent-sums across the wave pair
    if (oddw) {
#pragma unroll
        for (int i = 0; i < 8; ++i) lds[pair][i][lane] = sum[i];
    }
    __syncthreads();
    if (!oddw) {
#pragma unroll
        for (int i = 0; i < 8; ++i) sum[i] += lds[pair][i][lane];

        // selected-agent MLP
        Frags Fs;
        load_frags(Fs, sW1, sb1, sW2, sb2, sW3, sb3, lane);

        float4 xs = make_float4(0.f, 0.f, 0.f, 0.f);
        if (!h) xs = *(const float4*)(xrow + 4 * sel);
        vfloat16 C3s = run_mlp3(make_b1(xs), Fs, h);

        // gate layer 1: concat([sel_out, sum_other]) @ gW1 + gb1, relu
        bf16x8 Ag_lo = make_afrag(gW1, 32, 32, 32, 0, lane);
        bf16x8 Ag_hi = make_afrag(gW1, 32, 32, 32, 16, lane);
        vfloat16 gb1v = bvec32(gb1, lane);
        bf16x8 Bg_lo = xposeB(C3s[0], C3s[1], C3s[2], C3s[3],
                              C3s[4], C3s[5], C3s[6], C3s[7], h);   // relu folded
        bf16x8 Bg_hi = xposeB(sum[0], sum[1], sum[2], sum[3],
                              sum[4], sum[5], sum[6], sum[7], h);   // sums >= 0
        vfloat16 G = mfma32(Ag_lo, Bg_lo, gb1v);
        G = mfma32(Ag_hi, Bg_hi, G);
#pragma unroll
        for (int i = 0; i < 16; ++i) G[i] = fmaxf(G[i], 0.f);

        // gate layer 2 (32 -> 2) in fp32 VALU + cross-half reduce
        float q0 = 0.f, q1 = 0.f;
#pragma unroll
        for (int reg = 0; reg < 16; ++reg) {
            int row = (reg & 3) + 8 * (reg >> 2) + (h ? 4 : 0);
            q0 += G[reg] * gW2[row * 2 + 0];
            q1 += G[reg] * gW2[row * 2 + 1];
        }
        q0 += __shfl_xor(q0, 32, 64);
        q1 += __shfl_xor(q1, 32, 64);
        q0 += gb2[0];
        q1 += gb2[1];

        if (!h) {
            int act = (int)xs.w;           // x in [0,1) -> 0; clamp like take_along_axis
            act = act < 0 ? 0 : (act > 1 ? 1 : act);
            out[base + c] = act ? q1 : q0;
        }
    }
}

extern "C" void kernel_launch(void* const* d_in, const int* in_sizes, int n_in,
                              void* d_out, int out_size, void* d_ws, size_t ws_size,
                              hipStream_t stream) {
    const float* x   = (const float*)d_in[0];
    const int*   sel = (const int*)d_in[1];
    const float* oW1 = (const float*)d_in[2];
    const float* ob1 = (const float*)d_in[3];
    const float* oW2 = (const float*)d_in[4];
    const float* ob2 = (const float*)d_in[5];
    const float* oW3 = (const float*)d_in[6];
    const float* ob3 = (const float*)d_in[7];
    const float* sW1 = (const float*)d_in[8];
    const float* sb1 = (const float*)d_in[9];
    const float* sW2 = (const float*)d_in[10];
    const float* sb2 = (const float*)d_in[11];
    const float* sW3 = (const float*)d_in[12];
    const float* sb3 = (const float*)d_in[13];
    const float* gW1 = (const float*)d_in[14];
    const float* gb1 = (const float*)d_in[15];
    const float* gW2 = (const float*)d_in[16];
    const float* gb2 = (const float*)d_in[17];
    float* out = (float*)d_out;

    const int B = in_sizes[0] / 128;       // 65536
    const int blocks = B / 64;             // 64 batch rows per block (2 wave-pairs)
    dqn_kernel<<<blocks, 256, 0, stream>>>(x, sel,
                                           oW1, ob1, oW2, ob2, oW3, ob3,
                                           sW1, sb1, sW2, sb2, sW3, sb3,
                                           gW1, gb1, gW2, gb2, out);
}